// Round 1
// baseline (186.718 us; speedup 1.0000x reference)
//
#include <hip/hip_runtime.h>

// PointPillarScatter3d on MI355X (gfx950)
// NZ=1, NY=NX=512, C=128, B=4, P=320000.
// Strategy: scatter->gather inversion.
//   k_init_map:    map[B*CELLS] = -1
//   k_scatter_idx: map[b*CELLS + z*NY*NX + y*NX + x] = point index (cells unique per batch)
//   k_gather:      per 64-cell tile: gather feature rows (coalesced float4 reads),
//                  LDS transpose ([64][129] pad -> <=2-way bank aliasing, free),
//                  coalesced float4 streaming writes of the full output (zeros where empty).

#define NXD 512
#define NYD 512
#define NZD 1
#define CB  128
#define CELLS (NXD * NYD * NZD)   // 262144

__global__ void k_init_map(int* __restrict__ map, int n4) {
    int i = blockIdx.x * blockDim.x + threadIdx.x;
    if (i < n4) ((int4*)map)[i] = make_int4(-1, -1, -1, -1);
}

__global__ void k_scatter_idx(const int* __restrict__ coords,
                              int* __restrict__ map, int P) {
    int p = blockIdx.x * blockDim.x + threadIdx.x;
    if (p >= P) return;
    int4 c = ((const int4*)coords)[p];      // (b, z, y, x)
    int cell = c.y * (NYD * NXD) + c.z * NXD + c.w;
    map[c.x * CELLS + cell] = p;
}

__global__ __launch_bounds__(256) void k_gather(const float* __restrict__ feat,
                                                const int* __restrict__ map,
                                                float* __restrict__ out) {
    __shared__ int   pidx[64];
    __shared__ float tile[64][CB + 1];      // +1 pad: phase-C strided reads spread banks

    const int t = threadIdx.x;
    const int tiles_per_b = CELLS / 64;
    const int b = blockIdx.x / tiles_per_b;
    const int cell_base = (blockIdx.x % tiles_per_b) * 64;

    if (t < 64) pidx[t] = map[b * CELLS + cell_base + t];
    __syncthreads();

    // Phase B: gather feature rows into LDS. 32 lanes x float4 = one 512B row,
    // 8 rows in flight per pass, 8 passes -> 64 rows.
    {
        const int c4 = t & 31;       // float4 column within row
        const int r0 = t >> 5;       // 0..7
        #pragma unroll
        for (int rr = 0; rr < 8; ++rr) {
            const int x = rr * 8 + r0;
            const int idx = pidx[x];
            float4 v = make_float4(0.f, 0.f, 0.f, 0.f);
            if (idx >= 0) v = ((const float4*)feat)[(size_t)idx * (CB / 4) + c4];
            tile[x][c4 * 4 + 0] = v.x;
            tile[x][c4 * 4 + 1] = v.y;
            tile[x][c4 * 4 + 2] = v.z;
            tile[x][c4 * 4 + 3] = v.w;
        }
    }
    __syncthreads();

    // Phase C: transposed write-out. Lane owns a float4 along x for channel c;
    // 16 lanes x 16B = 256B contiguous per channel group -> coalesced.
    {
        const int x4 = t & 15;       // float4 index along x (16 per 64-cell tile)
        const int cr = t >> 4;       // 0..15
        float* outb = out + (size_t)b * CB * CELLS + cell_base + x4 * 4;
        #pragma unroll
        for (int cc = 0; cc < 8; ++cc) {
            const int c = cc * 16 + cr;
            float4 v;
            v.x = tile[x4 * 4 + 0][c];
            v.y = tile[x4 * 4 + 1][c];
            v.z = tile[x4 * 4 + 2][c];
            v.w = tile[x4 * 4 + 3][c];
            *reinterpret_cast<float4*>(outb + (size_t)c * CELLS) = v;
        }
    }
}

extern "C" void kernel_launch(void* const* d_in, const int* in_sizes, int n_in,
                              void* d_out, int out_size, void* d_ws, size_t ws_size,
                              hipStream_t stream) {
    const float* feat   = (const float*)d_in[1];
    const int*   coords = (const int*)d_in[2];
    float*       out    = (float*)d_out;
    int*         map    = (int*)d_ws;   // B*CELLS int32 = 4 MB

    const int B = out_size / (CB * CELLS);
    const int P = in_sizes[1] / CB;
    const int n_map = B * CELLS;

    k_init_map<<<(n_map / 4 + 255) / 256, 256, 0, stream>>>(map, n_map / 4);
    k_scatter_idx<<<(P + 255) / 256, 256, 0, stream>>>(coords, map, P);
    k_gather<<<B * (CELLS / 64), 256, 0, stream>>>(feat, map, out);
}

// Round 2
// 185.831 us; speedup vs baseline: 1.0048x; 1.0048x over previous
//
#include <hip/hip_runtime.h>

// PointPillarScatter3d on MI355X (gfx950)
// NZ=1, NY=NX=512, C=128, B=4, P=320000.
// Strategy: scatter->gather inversion.
//   hipMemsetAsync: map[B*CELLS] = -1 (0xFF fill, 6.8 TB/s fill path)
//   k_scatter_idx:  map[b*CELLS + z*NY*NX + y*NX + x] = point index (cells unique per batch)
//   k_gather:       per 64-cell tile: gather feature rows (coalesced float4 reads),
//                   XOR-swizzled LDS transpose, coalesced float4 streaming writes
//                   of the full output (zeros where empty -> no separate zero pass).
//
// LDS layout: tile4[(x, c4)] at float4-offset x*32 + (c4 ^ (x>>2)).
//   Phase B write: one ds_write_b128/thread, slot=(c4&7)^const -> 8 lanes/slot, conflict-free.
//   Phase C read:  scalar, bank = 4*((c4^x4)&7) + q -> 2 lanes/bank = free (m136).

#define NXD 512
#define NYD 512
#define NZD 1
#define CB  128
#define CELLS (NXD * NYD * NZD)   // 262144

__global__ void k_scatter_idx(const int* __restrict__ coords,
                              int* __restrict__ map, int P) {
    int p = blockIdx.x * blockDim.x + threadIdx.x;
    if (p >= P) return;
    int4 c = ((const int4*)coords)[p];      // (b, z, y, x)
    int cell = c.y * (NYD * NXD) + c.z * NXD + c.w;
    map[c.x * CELLS + cell] = p;
}

__global__ __launch_bounds__(256) void k_gather(const float* __restrict__ feat,
                                                const int* __restrict__ map,
                                                float* __restrict__ out) {
    __shared__ int    pidx[64];
    __shared__ float4 tile4[64 * 32];   // 32 KB, swizzled

    const int t = threadIdx.x;
    const int tiles_per_b = CELLS / 64;
    const int b = blockIdx.x / tiles_per_b;
    const int cell_base = (blockIdx.x % tiles_per_b) * 64;

    if (t < 64) pidx[t] = map[b * CELLS + cell_base + t];
    __syncthreads();

    // Phase B: gather feature rows into LDS. 32 lanes x float4 = one 512B row,
    // 8 rows in flight per pass, 8 passes -> 64 rows. One ds_write_b128 each.
    {
        const int c4 = t & 31;       // float4 column within row
        const int r0 = t >> 5;       // 0..7
        #pragma unroll
        for (int rr = 0; rr < 8; ++rr) {
            const int x = rr * 8 + r0;
            const int idx = pidx[x];
            float4 v = make_float4(0.f, 0.f, 0.f, 0.f);
            if (idx >= 0) v = ((const float4*)feat)[(size_t)idx * (CB / 4) + c4];
            tile4[x * 32 + (c4 ^ (x >> 2))] = v;
        }
    }
    __syncthreads();

    // Phase C: transposed write-out. Lane owns a float4 along x for channel c;
    // 16 lanes x 16B = 256B contiguous per channel -> coalesced streaming writes.
    {
        const int x4 = t & 15;       // float4 index along x (16 per 64-cell tile)
        const int cr = t >> 4;       // 0..15
        float* outb = out + (size_t)b * (size_t)CB * CELLS + cell_base + x4 * 4;
        #pragma unroll
        for (int cc = 0; cc < 8; ++cc) {
            const int c  = cc * 16 + cr;
            const int c4 = c >> 2;
            const int ce = c & 3;
            float4 v;
            v.x = ((const float*)&tile4[(x4 * 4 + 0) * 32 + (c4 ^ x4)])[ce];
            v.y = ((const float*)&tile4[(x4 * 4 + 1) * 32 + (c4 ^ x4)])[ce];
            v.z = ((const float*)&tile4[(x4 * 4 + 2) * 32 + (c4 ^ x4)])[ce];
            v.w = ((const float*)&tile4[(x4 * 4 + 3) * 32 + (c4 ^ x4)])[ce];
            *reinterpret_cast<float4*>(outb + (size_t)c * CELLS) = v;
        }
    }
}

extern "C" void kernel_launch(void* const* d_in, const int* in_sizes, int n_in,
                              void* d_out, int out_size, void* d_ws, size_t ws_size,
                              hipStream_t stream) {
    const float* feat   = (const float*)d_in[1];
    const int*   coords = (const int*)d_in[2];
    float*       out    = (float*)d_out;
    int*         map    = (int*)d_ws;   // B*CELLS int32 = 4 MB

    const int B = out_size / (CB * CELLS);
    const int P = in_sizes[1] / CB;
    const int n_map = B * CELLS;

    hipMemsetAsync(map, 0xFF, (size_t)n_map * sizeof(int), stream);
    k_scatter_idx<<<(P + 255) / 256, 256, 0, stream>>>(coords, map, P);
    k_gather<<<B * (CELLS / 64), 256, 0, stream>>>(feat, map, out);
}